// Round 9
// baseline (180.452 us; speedup 1.0000x reference)
//
#include <hip/hip_runtime.h>
#include <math.h>

// CTC loss, T=1024 B=64 V=256 L=256 (S=513).
// Round 15: round-8's 16-wave lse-folded frame + round-4's gather placement.
//  - Consumer (wave 0) = round-4 verbatim: per step 1 conflict-free
//    ds_read_b128 (pre-packed gather set) + 1 broadcast ds_read_b32 (blank)
//    + MACS. Proven ~650 cyc/window.
//  - Producers (waves 1..15, one row/window, wave15 dual): prefetched
//    coalesced load -> 4 exps -> ds_write_b128 to PRIVATE scratch row ->
//    issue 5 scattered LDS reads -> compute lse (DPP reduce + logf) WHILE
//    the reads are in flight (VALU covers the LDS round-trip that was dead
//    serial time in round 4) -> pack float4 -> ds_write_b128 into gbuf.
//  - lse folded (round 8): producer slot s == old lse wave (b,q=s), same row
//    order, same reduce ops -> per-slot sums bit-identical; FETCH stays 33MB.
//  - Consumer schedule, MACS order, renorm points (t=15,31,...), init/tail,
//    accbuf sum order: bit-identical to the passing rounds 4/8.
// Fallback (shape mismatch): round-4 kernels verbatim (fb_ prefix).

constexpr int V = 256;
constexpr float LN2_F = 0.6931471805599453f;

typedef unsigned uint2v __attribute__((ext_vector_type(2)));

template <int CTRL>
__device__ __forceinline__ float dpp_mov_f(float x) {
    return __int_as_float(__builtin_amdgcn_update_dpp(
        0, __float_as_int(x), CTRL, 0xF, 0xF, true));
}

// whole-wave shift down by 1 lane (lane l reads lane l-1; lane 0 -> 0). VALU.
__device__ __forceinline__ float wave_shr1_f(float x) {
    return __int_as_float(__builtin_amdgcn_update_dpp(
        0, __float_as_int(x), 0x138, 0xF, 0xF, true));  // wave_shr:1
}

__device__ __forceinline__ float wave_max_f(float m) {
    m = fmaxf(m, dpp_mov_f<0xB1>(m));    // quad_perm xor1
    m = fmaxf(m, dpp_mov_f<0x4E>(m));    // quad_perm xor2
    m = fmaxf(m, dpp_mov_f<0x124>(m));   // row_ror:4
    m = fmaxf(m, dpp_mov_f<0x128>(m));   // row_ror:8
#if __has_builtin(__builtin_amdgcn_permlane16_swap) && __has_builtin(__builtin_amdgcn_permlane32_swap)
    uint2v a = __builtin_amdgcn_permlane16_swap(__float_as_uint(m),
                                                __float_as_uint(m), false, false);
    m = fmaxf(__uint_as_float(a.x), __uint_as_float(a.y));
    uint2v b = __builtin_amdgcn_permlane32_swap(__float_as_uint(m),
                                                __float_as_uint(m), false, false);
    m = fmaxf(__uint_as_float(b.x), __uint_as_float(b.y));
#else
    m = fmaxf(m, __shfl_xor(m, 16, 64));
    m = fmaxf(m, __shfl_xor(m, 32, 64));
#endif
    return m;
}

__device__ __forceinline__ float wave_sum_f(float s) {
    s += dpp_mov_f<0xB1>(s);
    s += dpp_mov_f<0x4E>(s);
    s += dpp_mov_f<0x124>(s);
    s += dpp_mov_f<0x128>(s);
#if __has_builtin(__builtin_amdgcn_permlane16_swap) && __has_builtin(__builtin_amdgcn_permlane32_swap)
    uint2v a = __builtin_amdgcn_permlane16_swap(__float_as_uint(s),
                                                __float_as_uint(s), false, false);
    s = __uint_as_float(a.x) + __uint_as_float(a.y);
    uint2v b = __builtin_amdgcn_permlane32_swap(__float_as_uint(s),
                                                __float_as_uint(s), false, false);
    s = __uint_as_float(b.x) + __uint_as_float(b.y);
#else
    s += __shfl_xor(s, 16, 64);
    s += __shfl_xor(s, 32, 64);
#endif
    return s;
}

#define MACS(EB, E1, E3, E5, E7) do {                                  \
    const float c7m = wave_shr1_f(cur7);                               \
    curT = (curT + cur7) * (EB);                                       \
    cur7 = fmaf(sk7, cur5, cur7 + cur6) * (E7);                        \
    cur6 = (cur6 + cur5) * (EB);                                       \
    cur5 = fmaf(sk5, cur3, cur5 + cur4) * (E5);                        \
    cur4 = (cur4 + cur3) * (EB);                                       \
    cur3 = fmaf(sk3, cur1, cur3 + cur2) * (E3);                        \
    cur2 = (cur2 + cur1) * (EB);                                       \
    cur1 = fmaf(sk1, c7m, cur1 + cur0) * (E1);                         \
    cur0 = (cur0 + c7m) * (EB);                                        \
  } while (0)

#define RENORM do {                                                    \
    curT *= mkT; cur0 *= mk0; cur1 *= mk1; cur2 *= mk2; cur3 *= mk3;   \
    cur4 *= mk4; cur5 *= mk5; cur6 *= mk6; cur7 *= mk7;                \
    float _m = fmaxf(curT, cur0); _m = fmaxf(_m, cur1);                \
    _m = fmaxf(_m, cur2); _m = fmaxf(_m, cur3); _m = fmaxf(_m, cur4);  \
    _m = fmaxf(_m, cur5); _m = fmaxf(_m, cur6); _m = fmaxf(_m, cur7);  \
    _m = wave_max_f(_m);                                               \
    const float _inv = 1.f / fmaxf(_m, 1e-30f);                        \
    log2acc -= log2f(_inv);                                            \
    curT *= _inv; cur0 *= _inv; cur1 *= _inv; cur2 *= _inv;            \
    cur3 *= _inv; cur4 *= _inv; cur5 *= _inv; cur6 *= _inv;            \
    cur7 *= _inv;                                                      \
  } while (0)

// consumer: gather-set ring (8 deep), reading pre-packed gbuf/bbuf
#define PRE(N, S) do {                                                 \
    G##N = *(const float4*)(&gbuf[h][S][l][0]);                        \
    A##N = bbuf[h][S];                                                 \
  } while (0)
#define STEPR(N, S) do {                                               \
    MACS(A##N, G##N.x, G##N.y, G##N.z, G##N.w);                        \
    PRE(N, S);                                                         \
  } while (0)
#define STEPC(N) MACS(A##N, G##N.x, G##N.y, G##N.z, G##N.w)

#define WG_BARRIER asm volatile("s_waitcnt lgkmcnt(0)\n\ts_barrier" ::: "memory")

__global__ __launch_bounds__(1024) void ctc_main(
    const int*   __restrict__ labels,      // [B, L]
    const float* __restrict__ logits,      // [T, B, V]
    const int*   __restrict__ label_len,   // [B]
    const int*   __restrict__ logit_len,   // [B]
    float*       __restrict__ vres,        // [B] per-batch (lse_sum - lnterm)
    int T, int B, int L)
{
    const int tid = threadIdx.x;
    const int wid = tid >> 6;              // wave 0 consumer, 1..15 producers
    const int l   = tid & 63;
    const int b   = blockIdx.x;

    __shared__ __align__(16) float gbuf[2][16][64][4];  // packed gather sets
    __shared__ float bbuf[2][16];                       // blank per row
    __shared__ __align__(16) float prow[16][256];       // private exp'd rows
    __shared__ float afin[514];
    __shared__ float accbuf[16];                        // per-slot lse sums

    const int Tb = logit_len[b];
    const int Lb = label_len[b];
    const int NW = Tb / 16;

    const float* lg = logits + (size_t)b * V;
    const size_t rs = (size_t)B * V;

    // gather indices (all waves need them)
    const int4 lb4 = ((const int4*)(labels + (size_t)b * L))[l];
    const int ix = lb4.x, iy = lb4.y, iz = lb4.z, iw = lb4.w;

    if (wid == 0) {
        // ============================ consumer ============================
        __builtin_amdgcn_s_setprio(1);
        const int Sb = 2 * Lb + 1;

        const int prevw = __shfl_up(iw, 1);
        const float sk1 = (l > 0 && ix != prevw) ? 1.f : 0.f;
        const float sk3 = (iy != ix) ? 1.f : 0.f;
        const float sk5 = (iz != iy) ? 1.f : 0.f;
        const float sk7 = (iw != iz) ? 1.f : 0.f;

        const float mk0 = (8 * l + 0 < Sb) ? 1.f : 0.f;
        const float mk1 = (8 * l + 1 < Sb) ? 1.f : 0.f;
        const float mk2 = (8 * l + 2 < Sb) ? 1.f : 0.f;
        const float mk3 = (8 * l + 3 < Sb) ? 1.f : 0.f;
        const float mk4 = (8 * l + 4 < Sb) ? 1.f : 0.f;
        const float mk5 = (8 * l + 5 < Sb) ? 1.f : 0.f;
        const float mk6 = (8 * l + 6 < Sb) ? 1.f : 0.f;
        const float mk7 = (8 * l + 7 < Sb) ? 1.f : 0.f;
        const float mkT = (Sb > 512 && l == 63) ? 1.f : 0.f;

        // t=0 init (identical to rounds 4/8)
        float cur0 = 0.f, cur1 = 0.f, cur2 = 0.f, cur3 = 0.f;
        float cur4 = 0.f, cur5 = 0.f, cur6 = 0.f, cur7 = 0.f, curT = 0.f;
        if (l == 0) {
            cur0 = __expf(lg[0]);
            cur1 = __expf(lg[ix]) * mk1;
        }
        float log2acc = 0.f;

        float4 G0{}, G1{}, G2{}, G3{}, G4{}, G5{}, G6{}, G7{};
        float  A0 = 0, A1 = 0, A2 = 0, A3 = 0, A4 = 0, A5 = 0, A6 = 0, A7 = 0;

        for (int k = 0; k <= NW; ++k) {
            if (k >= 1) {
                const int w = k - 1;
                const int h = w & 1;
                if (w == 0) {
                    PRE(1, 1); PRE(2, 2); PRE(3, 3); PRE(4, 4);
                    PRE(5, 5); PRE(6, 6); PRE(7, 7); PRE(0, 8);
                    STEPR(1, 9);  STEPR(2, 10); STEPR(3, 11); STEPR(4, 12);
                    STEPR(5, 13); STEPR(6, 14); STEPR(7, 15);
                    STEPC(0);
                    STEPC(1); STEPC(2); STEPC(3); STEPC(4);
                    STEPC(5); STEPC(6); STEPC(7);
                } else {
                    PRE(0, 0); PRE(1, 1); PRE(2, 2); PRE(3, 3);
                    PRE(4, 4); PRE(5, 5); PRE(6, 6); PRE(7, 7);
                    STEPR(0, 8);  STEPR(1, 9);  STEPR(2, 10); STEPR(3, 11);
                    STEPR(4, 12); STEPR(5, 13); STEPR(6, 14); STEPR(7, 15);
                    STEPC(0); STEPC(1); STEPC(2); STEPC(3);
                    STEPC(4); STEPC(5); STEPC(6); STEPC(7);
                }
                RENORM;
            }
            WG_BARRIER;
        }

        // scalar tail (t = 16*NW..Tb-1), raw logits, identical numerics
        for (int t = 16 * NW; t < Tb; ++t) {
            if (t < 1) continue;
            const float* rowp = lg + rs * (size_t)t;
            const float eb = __expf(rowp[0]);
            const float e1 = __expf(rowp[ix]), e3 = __expf(rowp[iy]);
            const float e5 = __expf(rowp[iz]), e7 = __expf(rowp[iw]);
            MACS(eb, e1, e3, e5, e7);
        }

        afin[8 * l + 0] = cur0; afin[8 * l + 1] = cur1;
        afin[8 * l + 2] = cur2; afin[8 * l + 3] = cur3;
        afin[8 * l + 4] = cur4; afin[8 * l + 5] = cur5;
        afin[8 * l + 6] = cur6; afin[8 * l + 7] = cur7;
        if (l == 63) afin[512] = curT;
        const int end = 2 * Lb;
        const int em1 = (end > 0) ? end - 1 : 0;
        float ssum = afin[end] + afin[em1];     // same-wave DS, in-order
        ssum = fmaxf(ssum, 1e-37f);
        const float lnt = logf(ssum) + LN2_F * log2acc;

        WG_BARRIER;                        // accbuf ready (producers wrote)

        // lse sum in the OLD ctc_final order: q = 0..15 ascending
        float c = 0.f;
        #pragma unroll
        for (int q = 0; q < 16; ++q) c += accbuf[q];
        if (l == 0) vres[b] = c - lnt;
    } else {
        // ============================ producers ===========================
        const int s0   = wid - 1;          // slot 0..14
        const bool dual = (wid == 15);     // wave 15 also handles slot 15
        float accA = 0.f, accB = 0.f;

        float4 pc0{}, pn0{}, pc1{}, pn1{};
        if (NW > 0) {
            pc0 = *(const float4*)(lg + rs * (size_t)s0 + 4 * l);
            pn0 = *(const float4*)(lg + rs * (size_t)(16 + s0) + 4 * l);
            if (dual) {
                pc1 = *(const float4*)(lg + rs * (size_t)15 + 4 * l);
                pn1 = *(const float4*)(lg + rs * (size_t)31 + 4 * l);
            }
        }

        for (int k = 0; k <= NW; ++k) {
            if (k < NW) {
                const int hh = k & 1;
                const float4 x0 = pc0;
                pc0 = pn0;
                if (k + 2 < NW)
                    pn0 = *(const float4*)(lg + rs * (size_t)(16 * (k + 2) + s0) + 4 * l);
                float4 x1{};
                if (dual) {
                    x1 = pc1;
                    pc1 = pn1;
                    if (k + 2 < NW)
                        pn1 = *(const float4*)(lg + rs * (size_t)(16 * (k + 2) + 15) + 4 * l);
                }
                // exp'd full rows -> PRIVATE scratch (ds_write_b128)
                float4 e0;
                e0.x = __expf(x0.x); e0.y = __expf(x0.y);
                e0.z = __expf(x0.z); e0.w = __expf(x0.w);
                *(float4*)&prow[s0][4 * l] = e0;
                if (dual) {
                    float4 e1v;
                    e1v.x = __expf(x1.x); e1v.y = __expf(x1.y);
                    e1v.z = __expf(x1.z); e1v.w = __expf(x1.w);
                    *(float4*)&prow[15][4 * l] = e1v;
                }
                // issue gather reads (same-wave in-order DS sees the writes)
                const float ga = prow[s0][ix], gb2 = prow[s0][iy];
                const float gc = prow[s0][iz], gd = prow[s0][iw];
                const float ge = prow[s0][0];
                float ha = 0, hb = 0, hc = 0, hd = 0, he = 0;
                if (dual) {
                    ha = prow[15][ix]; hb = prow[15][iy];
                    hc = prow[15][iz]; hd = prow[15][iw];
                    he = prow[15][0];
                }
                // lse on raw rows (VALU work overlaps the LDS round-trip;
                // identical ops/order as old lse wave (b, q=slot))
                {
                    float m = fmaxf(fmaxf(x0.x, x0.y), fmaxf(x0.z, x0.w));
                    m = wave_max_f(m);
                    float ss = __expf(x0.x - m) + __expf(x0.y - m) +
                               __expf(x0.z - m) + __expf(x0.w - m);
                    ss = wave_sum_f(ss);
                    const int t = 16 * k + s0;
                    if (t < Tb) accA += m + logf(ss);
                }
                if (dual) {
                    float m = fmaxf(fmaxf(x1.x, x1.y), fmaxf(x1.z, x1.w));
                    m = wave_max_f(m);
                    float ss = __expf(x1.x - m) + __expf(x1.y - m) +
                               __expf(x1.z - m) + __expf(x1.w - m);
                    ss = wave_sum_f(ss);
                    const int t = 16 * k + 15;
                    if (t < Tb) accB += m + logf(ss);
                }
                // pack + publish gather sets (consumed after next barrier)
                float4 gv;
                gv.x = ga; gv.y = gb2; gv.z = gc; gv.w = gd;
                *(float4*)&gbuf[hh][s0][l][0] = gv;
                if (l == 0) bbuf[hh][s0] = ge;
                if (dual) {
                    float4 hv;
                    hv.x = ha; hv.y = hb; hv.z = hc; hv.w = hd;
                    *(float4*)&gbuf[hh][15][l][0] = hv;
                    if (l == 0) bbuf[hh][15] = he;
                }
            }
            WG_BARRIER;
        }

        // leftover lse rows (general Tb; none at Tb=1024)
        for (int t = 16 * NW + s0; t < Tb; t += 16) {
            const float4 x = *(const float4*)(lg + rs * (size_t)t + 4 * l);
            float m = fmaxf(fmaxf(x.x, x.y), fmaxf(x.z, x.w));
            m = wave_max_f(m);
            float ss = __expf(x.x - m) + __expf(x.y - m) +
                       __expf(x.z - m) + __expf(x.w - m);
            ss = wave_sum_f(ss);
            accA += m + logf(ss);
        }
        if (dual) {
            for (int t = 16 * NW + 15; t < Tb; t += 16) {
                const float4 x = *(const float4*)(lg + rs * (size_t)t + 4 * l);
                float m = fmaxf(fmaxf(x.x, x.y), fmaxf(x.z, x.w));
                m = wave_max_f(m);
                float ss = __expf(x.x - m) + __expf(x.y - m) +
                           __expf(x.z - m) + __expf(x.w - m);
                ss = wave_sum_f(ss);
                accB += m + logf(ss);
            }
        }
        if (l == 0) {
            accbuf[s0] = accA;
            if (dual) accbuf[15] = accB;
        }
        WG_BARRIER;                        // publish accbuf to consumer
    }
}

__global__ __launch_bounds__(64) void ctc_final(
    const float* __restrict__ vres,        // [B]
    float* __restrict__ out, int B)
{
    const int b = threadIdx.x;
    float v = (b < B) ? vres[b] : 0.f;
    #pragma unroll
    for (int o = 32; o >= 1; o >>= 1) v += __shfl_xor(v, o, 64);
    if (threadIdx.x == 0) out[0] = v / (float)B;
}

// =====================================================================
// FALLBACK PATH (round-4 kernels, verbatim; FB_ macro names)
// =====================================================================
#define FB_PRE(N, S) do {                                              \
    G##N = *(const float4*)(&gbuf[h][S][l][0]);                        \
    A##N = bbuf[h][S];                                                 \
  } while (0)
#define FB_STEPR(N, S) do {                                            \
    MACS(A##N, G##N.x, G##N.y, G##N.z, G##N.w);                        \
    FB_PRE(N, S);                                                      \
  } while (0)
#define FB_STEPC(N) MACS(A##N, G##N.x, G##N.y, G##N.z, G##N.w)

#define FB_PLOAD(dst, WV, J)                                           \
    dst = *(const float4*)(lg + rs * (size_t)(16 * (WV) + p + 7 * (J)) + 4 * l)
#define FB_PROC(XV, i) do {                                            \
    float4 _e;                                                         \
    _e.x = __expf((XV).x); _e.y = __expf((XV).y);                      \
    _e.z = __expf((XV).z); _e.w = __expf((XV).w);                      \
    *(float4*)&prow[p][4 * l] = _e;                                    \
    const float* _pr = prow[p];                                        \
    float _gb = _pr[0];                                                \
    float4 _gv;                                                        \
    _gv.x = _pr[ix]; _gv.y = _pr[iy]; _gv.z = _pr[iz]; _gv.w = _pr[iw];\
    *(float4*)&gbuf[h][i][l][0] = _gv;                                 \
    if (l == 0) bbuf[h][i] = _gb;                                      \
  } while (0)

__global__ __launch_bounds__(512) void fb_ctc_main(
    const int*   __restrict__ labels,
    const float* __restrict__ logits,
    const int*   __restrict__ label_len,
    const int*   __restrict__ logit_len,
    float*       __restrict__ partial,
    float*       __restrict__ lnterm,
    int T, int B, int L)
{
    const int tid = threadIdx.x;
    const int wid = tid >> 6;
    const int l   = tid & 63;

    if ((int)blockIdx.x < B) {
        __shared__ __align__(16) float gbuf[2][16][64][4];
        __shared__ float bbuf[2][16];
        __shared__ __align__(16) float prow[7][256];
        __shared__ float afin[514];

        const int b = blockIdx.x;
        const int Tb = logit_len[b];
        const int Lb = label_len[b];
        const int Sb = 2 * Lb + 1;

        const float* lg = logits + (size_t)b * V;
        const size_t rs = (size_t)B * V;

        const int4 lb4 = ((const int4*)(labels + (size_t)b * L))[l];
        const int ix = lb4.x, iy = lb4.y, iz = lb4.z, iw = lb4.w;
        const int prevw = __shfl_up(iw, 1);
        const float sk1 = (l > 0 && ix != prevw) ? 1.f : 0.f;
        const float sk3 = (iy != ix) ? 1.f : 0.f;
        const float sk5 = (iz != iy) ? 1.f : 0.f;
        const float sk7 = (iw != iz) ? 1.f : 0.f;

        const float mk0 = (8 * l + 0 < Sb) ? 1.f : 0.f;
        const float mk1 = (8 * l + 1 < Sb) ? 1.f : 0.f;
        const float mk2 = (8 * l + 2 < Sb) ? 1.f : 0.f;
        const float mk3 = (8 * l + 3 < Sb) ? 1.f : 0.f;
        const float mk4 = (8 * l + 4 < Sb) ? 1.f : 0.f;
        const float mk5 = (8 * l + 5 < Sb) ? 1.f : 0.f;
        const float mk6 = (8 * l + 6 < Sb) ? 1.f : 0.f;
        const float mk7 = (8 * l + 7 < Sb) ? 1.f : 0.f;
        const float mkT = (Sb > 512 && l == 63) ? 1.f : 0.f;

        float cur0 = 0.f, cur1 = 0.f, cur2 = 0.f, cur3 = 0.f;
        float cur4 = 0.f, cur5 = 0.f, cur6 = 0.f, cur7 = 0.f, curT = 0.f;
        if (l == 0) {
            cur0 = __expf(lg[0]);
            cur1 = __expf(lg[ix]) * mk1;
        }
        float log2acc = 0.f;

        const int NW = Tb / 16;

        float4 G0{}, G1{}, G2{}, G3{}, G4{}, G5{}, G6{}, G7{};
        float  A0 = 0, A1 = 0, A2 = 0, A3 = 0, A4 = 0, A5 = 0, A6 = 0, A7 = 0;

        const int p = (wid > 0) ? wid - 1 : 0;
        const bool three = (p < 2);
        float4 ca{}, cb{}, cc{}, na{}, nb{}, nc{};
        if (wid > 0 && NW > 0) {
            FB_PLOAD(ca, 0, 0);
            FB_PLOAD(cb, 0, 1);
            if (three) FB_PLOAD(cc, 0, 2);
        }
        if (wid == 0) __builtin_amdgcn_s_setprio(1);

        for (int k = 0; k <= NW; ++k) {
            if (wid != 0) {
                if (k < NW) {
                    const int h = k & 1;
                    if (k + 1 < NW) {
                        FB_PLOAD(na, k + 1, 0);
                        FB_PLOAD(nb, k + 1, 1);
                        if (three) FB_PLOAD(nc, k + 1, 2);
                    }
                    FB_PROC(ca, p);
                    FB_PROC(cb, p + 7);
                    if (three) FB_PROC(cc, p + 14);
                    ca = na; cb = nb; cc = nc;
                }
            } else if (k >= 1) {
                const int w = k - 1;
                const int h = w & 1;
                if (w == 0) {
                    FB_PRE(1, 1); FB_PRE(2, 2); FB_PRE(3, 3); FB_PRE(4, 4);
                    FB_PRE(5, 5); FB_PRE(6, 6); FB_PRE(7, 7); FB_PRE(0, 8);
                    FB_STEPR(1, 9);  FB_STEPR(2, 10); FB_STEPR(3, 11);
                    FB_STEPR(4, 12); FB_STEPR(5, 13); FB_STEPR(6, 14);
                    FB_STEPR(7, 15);
                    FB_STEPC(0);
                    FB_STEPC(1); FB_STEPC(2); FB_STEPC(3); FB_STEPC(4);
                    FB_STEPC(5); FB_STEPC(6); FB_STEPC(7);
                } else {
                    FB_PRE(0, 0); FB_PRE(1, 1); FB_PRE(2, 2); FB_PRE(3, 3);
                    FB_PRE(4, 4); FB_PRE(5, 5); FB_PRE(6, 6); FB_PRE(7, 7);
                    FB_STEPR(0, 8);  FB_STEPR(1, 9);  FB_STEPR(2, 10);
                    FB_STEPR(3, 11); FB_STEPR(4, 12); FB_STEPR(5, 13);
                    FB_STEPR(6, 14); FB_STEPR(7, 15);
                    FB_STEPC(0); FB_STEPC(1); FB_STEPC(2); FB_STEPC(3);
                    FB_STEPC(4); FB_STEPC(5); FB_STEPC(6); FB_STEPC(7);
                }
                RENORM;
            }
            WG_BARRIER;
        }

        if (wid == 0) {
            for (int t = 16 * NW; t < Tb; ++t) {
                if (t < 1) continue;
                const float* rowp = lg + rs * (size_t)t;
                const float eb = __expf(rowp[0]);
                const float e1 = __expf(rowp[ix]), e3 = __expf(rowp[iy]);
                const float e5 = __expf(rowp[iz]), e7 = __expf(rowp[iw]);
                MACS(eb, e1, e3, e5, e7);
            }

            afin[8 * l + 0] = cur0; afin[8 * l + 1] = cur1;
            afin[8 * l + 2] = cur2; afin[8 * l + 3] = cur3;
            afin[8 * l + 4] = cur4; afin[8 * l + 5] = cur5;
            afin[8 * l + 6] = cur6; afin[8 * l + 7] = cur7;
            if (l == 63) afin[512] = curT;
            const int end = 2 * Lb;
            const int em1 = (end > 0) ? end - 1 : 0;
            float ssum = afin[end] + afin[em1];
            ssum = fmaxf(ssum, 1e-37f);
            if (l == 0) lnterm[b] = logf(ssum) + LN2_F * log2acc;
        }
    } else {
        const int w  = ((int)blockIdx.x - B) * 8 + wid;
        const int nW = ((int)gridDim.x - B) * 8;
        const int rows = T * B;
        const int bb = w % B;
        const int Tbb = logit_len[bb];
        float acc = 0.f;
        int r = w;
        if (r < rows) {
            int t = w / B;
            const int ts = nW / B;
            float4 nxt = ((const float4*)(logits + (size_t)r * V))[l];
            while (true) {
                const int rn = r + nW;
                const bool more = rn < rows;
                const float4 x = nxt;
                if (more) nxt = ((const float4*)(logits + (size_t)rn * V))[l];
                float m = fmaxf(fmaxf(x.x, x.y), fmaxf(x.z, x.w));
                m = wave_max_f(m);
                float ss = __expf(x.x - m) + __expf(x.y - m) +
                           __expf(x.z - m) + __expf(x.w - m);
                ss = wave_sum_f(ss);
                if (t < Tbb) acc += m + logf(ss);
                if (!more) break;
                r = rn; t += ts;
            }
        }
        if (l == 0) partial[w] = acc;
    }
}

__global__ __launch_bounds__(64) void fb_ctc_final(
    const float* __restrict__ partial,
    const float* __restrict__ lnterm,
    float* __restrict__ out, int B, int nW)
{
    const int b = threadIdx.x;
    float v = 0.f;
    if (b < B) {
        float c = 0.f;
        for (int k = b; k < nW; k += B) c += partial[k];
        v = c - lnterm[b];
    }
    #pragma unroll
    for (int o = 32; o >= 1; o >>= 1) v += __shfl_xor(v, o, 64);
    if (threadIdx.x == 0) out[0] = v / (float)B;
}

extern "C" void kernel_launch(void* const* d_in, const int* in_sizes, int n_in,
                              void* d_out, int out_size, void* d_ws, size_t ws_size,
                              hipStream_t stream) {
    const int*   labels    = (const int*)d_in[0];
    const float* logits    = (const float*)d_in[1];
    const int*   label_len = (const int*)d_in[2];
    const int*   logit_len = (const int*)d_in[3];

    const int B = in_sizes[2];                 // 64
    const int L = in_sizes[0] / B;             // 256
    const int T = in_sizes[1] / (B * V);       // 1024

    if (T == 1024 && B == 64 && L == 256 && ws_size >= (size_t)B * sizeof(float)) {
        float* vres = (float*)d_ws;            // [B]
        ctc_main<<<B, 1024, 0, stream>>>(labels, logits, label_len, logit_len,
                                         vres, T, B, L);
        ctc_final<<<1, 64, 0, stream>>>(vres, (float*)d_out, B);
    } else {
        const int nLse = 1024;
        float* partial = (float*)d_ws;         // [nLse]
        float* lnterm  = partial + nLse;       // [B]
        fb_ctc_main<<<B + nLse / 8, 512, 0, stream>>>(labels, logits,
                                                      label_len, logit_len,
                                                      partial, lnterm,
                                                      T, B, L);
        fb_ctc_final<<<1, 64, 0, stream>>>(partial, lnterm, (float*)d_out,
                                           B, nLse);
    }
}